// Round 1
// baseline (445.940 us; speedup 1.0000x reference)
//
#include <hip/hip_runtime.h>
#include <hip/hip_bf16.h>
#include <math.h>

// Problem constants: B=2, N=2048, C=1024, H=16, D=64; M = B*N = 4096.

typedef __attribute__((ext_vector_type(8))) short bf16x8;  // 8 bf16 (4 VGPR)
typedef __attribute__((ext_vector_type(4))) float f32x4;

__device__ __forceinline__ short f2bf(float f) {
    union { float f; unsigned u; } x; x.f = f;
    unsigned r = x.u + 0x7fffu + ((x.u >> 16) & 1u);   // round-to-nearest-even
    return (short)(r >> 16);
}

// ---------------------------------------------------------------------------
// Weight prep: W (K x N, f32) -> Wt (N x K, bf16), 4 matrices via blockIdx.z
// ---------------------------------------------------------------------------
__global__ __launch_bounds__(256) void prep_w(const float* __restrict__ Wq,
                                              const float* __restrict__ Wk,
                                              const float* __restrict__ Wv,
                                              const float* __restrict__ Wo,
                                              short* __restrict__ wt) {
    __shared__ float tile[32][33];
    const float* W = blockIdx.z == 0 ? Wq : blockIdx.z == 1 ? Wk
                   : blockIdx.z == 2 ? Wv : Wo;
    short* dst = wt + (size_t)blockIdx.z * 1048576;
    const int bx = blockIdx.x * 32, by = blockIdx.y * 32;
    const int tx = threadIdx.x & 31, ty = threadIdx.x >> 5;  // 32 x 8
#pragma unroll
    for (int i = 0; i < 32; i += 8)
        tile[ty + i][tx] = W[(size_t)(by + ty + i) * 1024 + bx + tx];
    __syncthreads();
#pragma unroll
    for (int i = 0; i < 32; i += 8)
        dst[(size_t)(bx + ty + i) * 1024 + by + tx] = f2bf(tile[tx][ty + i]);
}

// ---------------------------------------------------------------------------
// GEMM: out = A(4096x1024) @ Wt^T + bias, bf16 MFMA, f32 accum.
//   AF32=1: A is f32 (converted while staging). AF32=0: A is bf16.
//   mode 0: out bf16 scatter [b,h,n,d]   (Q with scale=0.125, K with 1.0)
//   mode 1: out bf16 scatter [b,h,d,n]   (V transposed for PV fragments)
//   mode 2: out f32 flat [row, col]      (final projection)
// ---------------------------------------------------------------------------
template <int AF32>
__global__ __launch_bounds__(256) void gemm_kernel(const void* __restrict__ Aptr,
                                                   const short* __restrict__ Wt,
                                                   const float* __restrict__ bias,
                                                   void* __restrict__ outp,
                                                   int mode, float scale) {
    __shared__ short As[128 * 32];  // 8 KiB
    __shared__ short Bs[128 * 32];  // 8 KiB
    const int tid = threadIdx.x;
    const int l = tid & 63, w = tid >> 6;
    const int wr = w >> 1, wc = w & 1;
    const int row16 = l & 15, lg = l >> 4;
    const int m0 = blockIdx.x * 128;
    const int n0 = blockIdx.y * 128;

    f32x4 acc[4][4] = {};

    for (int k0 = 0; k0 < 1024; k0 += 32) {
        bf16x8 sa0, sa1, sb0, sb1;
        if constexpr (AF32) {
            const int r = tid >> 1, kk = (tid & 1) * 16;
            const float* src = (const float*)Aptr + (size_t)(m0 + r) * 1024 + k0 + kk;
            f32x4 x0 = ((const f32x4*)src)[0];
            f32x4 x1 = ((const f32x4*)src)[1];
            f32x4 x2 = ((const f32x4*)src)[2];
            f32x4 x3 = ((const f32x4*)src)[3];
#pragma unroll
            for (int j = 0; j < 4; ++j) {
                sa0[j] = f2bf(x0[j]); sa0[4 + j] = f2bf(x1[j]);
                sa1[j] = f2bf(x2[j]); sa1[4 + j] = f2bf(x3[j]);
            }
        } else {
            const short* Ab = (const short*)Aptr;
            const int i0 = tid, i1 = 256 + tid;
            sa0 = *(const bf16x8*)(Ab + (size_t)(m0 + (i0 >> 2)) * 1024 + k0 + (i0 & 3) * 8);
            sa1 = *(const bf16x8*)(Ab + (size_t)(m0 + (i1 >> 2)) * 1024 + k0 + (i1 & 3) * 8);
        }
        {
            const int i0 = tid, i1 = 256 + tid;
            sb0 = *(const bf16x8*)(Wt + (size_t)(n0 + (i0 >> 2)) * 1024 + k0 + (i0 & 3) * 8);
            sb1 = *(const bf16x8*)(Wt + (size_t)(n0 + (i1 >> 2)) * 1024 + k0 + (i1 & 3) * 8);
        }
        __syncthreads();  // WAR: prior iter's fragment reads done before overwrite
        if constexpr (AF32) {
            ((bf16x8*)As)[tid * 2]     = sa0;
            ((bf16x8*)As)[tid * 2 + 1] = sa1;
        } else {
            ((bf16x8*)As)[tid]       = sa0;
            ((bf16x8*)As)[256 + tid] = sa1;
        }
        ((bf16x8*)Bs)[tid]       = sb0;
        ((bf16x8*)Bs)[256 + tid] = sb1;
        __syncthreads();

        bf16x8 af[4], bfr[4];
#pragma unroll
        for (int m = 0; m < 4; ++m)
            af[m] = *(const bf16x8*)&As[(wr * 64 + m * 16 + row16) * 32 + lg * 8];
#pragma unroll
        for (int n = 0; n < 4; ++n)
            bfr[n] = *(const bf16x8*)&Bs[(wc * 64 + n * 16 + row16) * 32 + lg * 8];
#pragma unroll
        for (int m = 0; m < 4; ++m)
#pragma unroll
            for (int n = 0; n < 4; ++n)
                acc[m][n] = __builtin_amdgcn_mfma_f32_16x16x32_bf16(af[m], bfr[n], acc[m][n], 0, 0, 0);
    }

    // Epilogue. C/D layout: col = lane&15, row = (lane>>4)*4 + reg.
#pragma unroll
    for (int n = 0; n < 4; ++n) {
        const int col = n0 + wc * 64 + n * 16 + row16;
        const float bv = bias[col];
#pragma unroll
        for (int m = 0; m < 4; ++m) {
#pragma unroll
            for (int r = 0; r < 4; ++r) {
                const int row = m0 + wr * 64 + m * 16 + lg * 4 + r;
                const float val = (acc[m][n][r] + bv) * scale;
                if (mode == 2) {
                    ((float*)outp)[(size_t)row * 1024 + col] = val;
                } else {
                    const int b = row >> 11, nt = row & 2047;
                    const int h = col >> 6, d = col & 63;
                    short* o = (short*)outp;
                    if (mode == 0)
                        o[(((size_t)(b * 16 + h)) * 2048 + nt) * 64 + d] = f2bf(val);
                    else
                        o[(((size_t)(b * 16 + h)) * 64 + d) * 2048 + nt] = f2bf(val);
                }
            }
        }
    }
}

// ---------------------------------------------------------------------------
// Flash attention: one block = (b,h) x 64 q-rows; 4 waves x 16 rows each.
// qh/kh: [b,h,n,d] bf16 (q pre-scaled by 1/sqrt(D)); vt: [b,h,d,n] bf16.
// Output aout: [b,n,c] bf16 (row-major input for the final GEMM).
// ---------------------------------------------------------------------------
__global__ __launch_bounds__(256) void attn_kernel(const short* __restrict__ qh,
                                                   const short* __restrict__ kh,
                                                   const short* __restrict__ vt,
                                                   short* __restrict__ aout) {
    __shared__ short P[4][16][72];  // per-wave P tile, padded (2-way banks)
    const int tid = threadIdx.x;
    const int l = tid & 63, w = tid >> 6;
    const int row16 = l & 15, lg = l >> 4;
    const int bh = blockIdx.y;
    const int q0 = blockIdx.x * 64 + w * 16;

    bf16x8 qf[2];
#pragma unroll
    for (int kk = 0; kk < 2; ++kk)
        qf[kk] = *(const bf16x8*)&qh[((size_t)bh * 2048 + q0 + row16) * 64 + kk * 32 + lg * 8];

    f32x4 oac[4] = {};
    float m_run[4] = {-1e30f, -1e30f, -1e30f, -1e30f};
    float l_run[4] = {0.f, 0.f, 0.f, 0.f};

    for (int kv0 = 0; kv0 < 2048; kv0 += 64) {
        f32x4 s[4] = {};
#pragma unroll
        for (int t = 0; t < 4; ++t) {
#pragma unroll
            for (int kk = 0; kk < 2; ++kk) {
                bf16x8 kf = *(const bf16x8*)&kh[((size_t)bh * 2048 + kv0 + t * 16 + row16) * 64 + kk * 32 + lg * 8];
                s[t] = __builtin_amdgcn_mfma_f32_16x16x32_bf16(qf[kk], kf, s[t], 0, 0, 0);
            }
        }
        // Online softmax, wave-parallel: rows live in 16-lane groups.
        float mn[4], resc[4];
#pragma unroll
        for (int r = 0; r < 4; ++r) {
            float pm = fmaxf(fmaxf(s[0][r], s[1][r]), fmaxf(s[2][r], s[3][r]));
#pragma unroll
            for (int msk = 1; msk < 16; msk <<= 1)
                pm = fmaxf(pm, __shfl_xor(pm, msk, 64));
            mn[r] = fmaxf(m_run[r], pm);
            resc[r] = __expf(m_run[r] - mn[r]);
        }
        float p[4][4];
#pragma unroll
        for (int t = 0; t < 4; ++t)
#pragma unroll
            for (int r = 0; r < 4; ++r)
                p[t][r] = __expf(s[t][r] - mn[r]);
#pragma unroll
        for (int r = 0; r < 4; ++r) {
            float sum = p[0][r] + p[1][r] + p[2][r] + p[3][r];
#pragma unroll
            for (int msk = 1; msk < 16; msk <<= 1)
                sum += __shfl_xor(sum, msk, 64);
            l_run[r] = l_run[r] * resc[r] + sum;
            m_run[r] = mn[r];
        }
#pragma unroll
        for (int t = 0; t < 4; ++t)
#pragma unroll
            for (int r = 0; r < 4; ++r)
                oac[t][r] *= resc[r];
        // P (C-layout) -> LDS -> A-layout fragments.
#pragma unroll
        for (int t = 0; t < 4; ++t)
#pragma unroll
            for (int r = 0; r < 4; ++r)
                P[w][lg * 4 + r][t * 16 + row16] = f2bf(p[t][r]);
        __syncthreads();
        bf16x8 pf[2];
#pragma unroll
        for (int kk = 0; kk < 2; ++kk)
            pf[kk] = *(const bf16x8*)&P[w][row16][kk * 32 + lg * 8];
#pragma unroll
        for (int t = 0; t < 4; ++t) {
#pragma unroll
            for (int kk = 0; kk < 2; ++kk) {
                bf16x8 vf = *(const bf16x8*)&vt[((size_t)bh * 64 + t * 16 + row16) * 2048 + kv0 + kk * 32 + lg * 8];
                oac[t] = __builtin_amdgcn_mfma_f32_16x16x32_bf16(pf[kk], vf, oac[t], 0, 0, 0);
            }
        }
    }

    const int b = bh >> 4, h = bh & 15;
#pragma unroll
    for (int t = 0; t < 4; ++t) {
#pragma unroll
        for (int r = 0; r < 4; ++r) {
            const int qrow = q0 + lg * 4 + r;
            const int c = h * 64 + t * 16 + row16;
            const float val = oac[t][r] / l_run[r];
            aout[((size_t)b * 2048 + qrow) * 1024 + c] = f2bf(val);
        }
    }
}

// ---------------------------------------------------------------------------
extern "C" void kernel_launch(void* const* d_in, const int* in_sizes, int n_in,
                              void* d_out, int out_size, void* d_ws, size_t ws_size,
                              hipStream_t stream) {
    const float* q  = (const float*)d_in[0];
    const float* k  = (const float*)d_in[1];
    const float* v  = (const float*)d_in[2];
    const float* Wq = (const float*)d_in[3];
    const float* bq = (const float*)d_in[4];
    const float* Wk = (const float*)d_in[5];
    const float* bk = (const float*)d_in[6];
    const float* Wv = (const float*)d_in[7];
    const float* bv = (const float*)d_in[8];
    const float* Wo = (const float*)d_in[9];
    const float* bo = (const float*)d_in[10];

    char* ws = (char*)d_ws;
    short* wt   = (short*)ws;                     // 4 x 2 MiB bf16 W^T
    short* qh   = (short*)(ws + (8u  << 20));     // 8 MiB [b,h,n,d]
    short* khp  = (short*)(ws + (16u << 20));     // 8 MiB [b,h,n,d]
    short* vt   = (short*)(ws + (24u << 20));     // 8 MiB [b,h,d,n]
    short* aout = (short*)(ws + (32u << 20));     // 8 MiB [b,n,c]

    prep_w<<<dim3(32, 32, 4), 256, 0, stream>>>(Wq, Wk, Wv, Wo, wt);
    dim3 gg(32, 8);
    gemm_kernel<1><<<gg, 256, 0, stream>>>(q, wt,           bq, qh,   0, 0.125f);
    gemm_kernel<1><<<gg, 256, 0, stream>>>(k, wt + 1048576, bk, khp,  0, 1.0f);
    gemm_kernel<1><<<gg, 256, 0, stream>>>(v, wt + 2097152, bv, vt,   1, 1.0f);
    attn_kernel<<<dim3(32, 32), 256, 0, stream>>>(qh, khp, vt, aout);
    gemm_kernel<0><<<gg, 256, 0, stream>>>(aout, wt + 3145728, bo, d_out, 2, 1.0f);
}

// Round 3
// 300.289 us; speedup vs baseline: 1.4850x; 1.4850x over previous
//
#include <hip/hip_runtime.h>
#include <hip/hip_bf16.h>
#include <math.h>

// Problem constants: B=2, N=2048, C=1024, H=16, D=64; M = B*N = 4096.

typedef __attribute__((ext_vector_type(8))) short bf16x8;  // 8 bf16 (4 VGPR)
typedef __attribute__((ext_vector_type(4))) short bf16x4;  // 4 bf16 (2 VGPR)
typedef __attribute__((ext_vector_type(4))) float f32x4;

__device__ __forceinline__ short f2bf(float f) {
    union { float f; unsigned u; } x; x.f = f;
    unsigned r = x.u + 0x7fffu + ((x.u >> 16) & 1u);   // round-to-nearest-even
    return (short)(r >> 16);
}

// ---------------------------------------------------------------------------
// Weight prep: W (K x N, f32) -> Wt (N x K, bf16), 4 matrices via blockIdx.z
// ---------------------------------------------------------------------------
__global__ __launch_bounds__(256) void prep_w(const float* __restrict__ Wq,
                                              const float* __restrict__ Wk,
                                              const float* __restrict__ Wv,
                                              const float* __restrict__ Wo,
                                              short* __restrict__ wt) {
    __shared__ float tile[32][33];
    const float* W = blockIdx.z == 0 ? Wq : blockIdx.z == 1 ? Wk
                   : blockIdx.z == 2 ? Wv : Wo;
    short* dst = wt + (size_t)blockIdx.z * 1048576;
    const int bx = blockIdx.x * 32, by = blockIdx.y * 32;
    const int tx = threadIdx.x & 31, ty = threadIdx.x >> 5;  // 32 x 8
#pragma unroll
    for (int i = 0; i < 32; i += 8)
        tile[ty + i][tx] = W[(size_t)(by + ty + i) * 1024 + bx + tx];
    __syncthreads();
#pragma unroll
    for (int i = 0; i < 32; i += 8)
        dst[(size_t)(bx + ty + i) * 1024 + by + tx] = f2bf(tile[tx][ty + i]);
}

// ---------------------------------------------------------------------------
// GEMM: out = A(4096x1024) @ Wt^T + bias, bf16 MFMA, f32 accum.
//   AF32=1: A is f32 (converted while staging). AF32=0: A is bf16.
//   mode 0: out bf16 scatter [b,h,n,d]   (Q scaled by 0.125*log2e, K by 1.0)
//   mode 1: out bf16 scatter [b,h,d,n]   (V transposed for PV fragments)
//   mode 2: out f32 flat [row, col]      (final projection)
// ---------------------------------------------------------------------------
template <int AF32>
__global__ __launch_bounds__(256) void gemm_kernel(const void* __restrict__ Aptr,
                                                   const short* __restrict__ Wt,
                                                   const float* __restrict__ bias,
                                                   void* __restrict__ outp,
                                                   int mode, float scale) {
    __shared__ short As[128 * 32];  // 8 KiB
    __shared__ short Bs[128 * 32];  // 8 KiB
    const int tid = threadIdx.x;
    const int l = tid & 63, w = tid >> 6;
    const int wr = w >> 1, wc = w & 1;
    const int row16 = l & 15, lg = l >> 4;
    const int m0 = blockIdx.x * 128;
    const int n0 = blockIdx.y * 128;

    f32x4 acc[4][4] = {};

    for (int k0 = 0; k0 < 1024; k0 += 32) {
        bf16x8 sa0, sa1, sb0, sb1;
        if constexpr (AF32) {
            const int r = tid >> 1, kk = (tid & 1) * 16;
            const float* src = (const float*)Aptr + (size_t)(m0 + r) * 1024 + k0 + kk;
            f32x4 x0 = ((const f32x4*)src)[0];
            f32x4 x1 = ((const f32x4*)src)[1];
            f32x4 x2 = ((const f32x4*)src)[2];
            f32x4 x3 = ((const f32x4*)src)[3];
#pragma unroll
            for (int j = 0; j < 4; ++j) {
                sa0[j] = f2bf(x0[j]); sa0[4 + j] = f2bf(x1[j]);
                sa1[j] = f2bf(x2[j]); sa1[4 + j] = f2bf(x3[j]);
            }
        } else {
            const short* Ab = (const short*)Aptr;
            const int i0 = tid, i1 = 256 + tid;
            sa0 = *(const bf16x8*)(Ab + (size_t)(m0 + (i0 >> 2)) * 1024 + k0 + (i0 & 3) * 8);
            sa1 = *(const bf16x8*)(Ab + (size_t)(m0 + (i1 >> 2)) * 1024 + k0 + (i1 & 3) * 8);
        }
        {
            const int i0 = tid, i1 = 256 + tid;
            sb0 = *(const bf16x8*)(Wt + (size_t)(n0 + (i0 >> 2)) * 1024 + k0 + (i0 & 3) * 8);
            sb1 = *(const bf16x8*)(Wt + (size_t)(n0 + (i1 >> 2)) * 1024 + k0 + (i1 & 3) * 8);
        }
        __syncthreads();  // WAR: prior iter's fragment reads done before overwrite
        if constexpr (AF32) {
            ((bf16x8*)As)[tid * 2]     = sa0;
            ((bf16x8*)As)[tid * 2 + 1] = sa1;
        } else {
            ((bf16x8*)As)[tid]       = sa0;
            ((bf16x8*)As)[256 + tid] = sa1;
        }
        ((bf16x8*)Bs)[tid]       = sb0;
        ((bf16x8*)Bs)[256 + tid] = sb1;
        __syncthreads();

        bf16x8 af[4], bfr[4];
#pragma unroll
        for (int m = 0; m < 4; ++m)
            af[m] = *(const bf16x8*)&As[(wr * 64 + m * 16 + row16) * 32 + lg * 8];
#pragma unroll
        for (int n = 0; n < 4; ++n)
            bfr[n] = *(const bf16x8*)&Bs[(wc * 64 + n * 16 + row16) * 32 + lg * 8];
#pragma unroll
        for (int m = 0; m < 4; ++m)
#pragma unroll
            for (int n = 0; n < 4; ++n)
                acc[m][n] = __builtin_amdgcn_mfma_f32_16x16x32_bf16(af[m], bfr[n], acc[m][n], 0, 0, 0);
    }

    // Epilogue. C/D layout: col = lane&15, row = (lane>>4)*4 + reg.
#pragma unroll
    for (int n = 0; n < 4; ++n) {
        const int col = n0 + wc * 64 + n * 16 + row16;
        const float bv = bias[col];
#pragma unroll
        for (int m = 0; m < 4; ++m) {
#pragma unroll
            for (int r = 0; r < 4; ++r) {
                const int row = m0 + wr * 64 + m * 16 + lg * 4 + r;
                const float val = (acc[m][n][r] + bv) * scale;
                if (mode == 2) {
                    ((float*)outp)[(size_t)row * 1024 + col] = val;
                } else {
                    const int b = row >> 11, nt = row & 2047;
                    const int h = col >> 6, d = col & 63;
                    short* o = (short*)outp;
                    if (mode == 0)
                        o[(((size_t)(b * 16 + h)) * 2048 + nt) * 64 + d] = f2bf(val);
                    else
                        o[(((size_t)(b * 16 + h)) * 64 + d) * 2048 + nt] = f2bf(val);
                }
            }
        }
    }
}

// ---------------------------------------------------------------------------
// Flash attention v3: one block = (b,h) x 128 q-rows; 4 waves x 32 rows.
// Swapped QK^T (S^T = K·Q^T) -> lane-local softmax (2 shfl per reduction).
// K/V fragments read DIRECTLY from global (L2-resident: 256 KB/head each) —
// no cross-wave LDS, no barriers. Only per-wave P re-layout goes through LDS,
// explicitly fenced (cross-lane dep is invisible to per-thread alias analysis).
// qh: [b,h,n,d] bf16, q pre-scaled by 0.125*log2e (softmax in exp2 domain).
// vt: [b,h,d,n] bf16. Output aout: [b,n,c] bf16.
// ---------------------------------------------------------------------------
__global__ __launch_bounds__(256) void attn_kernel(const short* __restrict__ qh,
                                                   const short* __restrict__ kh,
                                                   const short* __restrict__ vt,
                                                   short* __restrict__ aout) {
    __shared__ short Pls[8][16 * 72];   // [wave*2+qt][q][k], padded rows

    const int tid = threadIdx.x;
    const int l = tid & 63, w = tid >> 6;
    const int row16 = l & 15, lg = l >> 4;
    const int bh = blockIdx.y;
    const int q0 = blockIdx.x * 128 + w * 32;

    const short* kbase = kh + (size_t)bh * 2048 * 64;
    const short* vbase = vt + (size_t)bh * 64 * 2048;

    // Hoisted Q B-frags: qf[qt][kk] = Q[q0+qt*16+row16][kk*32 + lg*8 ..]
    bf16x8 qf[2][2];
#pragma unroll
    for (int qt = 0; qt < 2; ++qt)
#pragma unroll
        for (int kk = 0; kk < 2; ++kk)
            qf[qt][kk] = *(const bf16x8*)&qh[((size_t)bh * 2048 + q0 + qt * 16 + row16) * 64 + kk * 32 + lg * 8];

    f32x4 oac[2][4] = {};
    float m_run[2] = {-1e30f, -1e30f};
    float l_run[2] = {0.f, 0.f};

    for (int t = 0; t < 32; ++t) {
        const int kvn = t * 64;

        // QK^T (swapped): s[qt][kt] = S^T[k=kt*16+lg*4+r][q=qt*16+row16].
        f32x4 s[2][4] = {};
#pragma unroll
        for (int kt = 0; kt < 4; ++kt) {
            const int krow = kvn + kt * 16 + row16;
#pragma unroll
            for (int kk = 0; kk < 2; ++kk) {
                bf16x8 kf = *(const bf16x8*)&kbase[(size_t)krow * 64 + kk * 32 + lg * 8];
                s[0][kt] = __builtin_amdgcn_mfma_f32_16x16x32_bf16(kf, qf[0][kk], s[0][kt], 0, 0, 0);
                s[1][kt] = __builtin_amdgcn_mfma_f32_16x16x32_bf16(kf, qf[1][kk], s[1][kt], 0, 0, 0);
            }
        }

        // Online softmax (exp2 domain), lane-local + 2 shfl per reduction.
        float resc[2];
#pragma unroll
        for (int qt = 0; qt < 2; ++qt) {
            float pm = -1e30f;
#pragma unroll
            for (int kt = 0; kt < 4; ++kt)
#pragma unroll
                for (int r = 0; r < 4; ++r) pm = fmaxf(pm, s[qt][kt][r]);
            pm = fmaxf(pm, __shfl_xor(pm, 16, 64));
            pm = fmaxf(pm, __shfl_xor(pm, 32, 64));
            const float mn = fmaxf(m_run[qt], pm);
            resc[qt] = exp2f(m_run[qt] - mn);
            float sum = 0.f;
#pragma unroll
            for (int kt = 0; kt < 4; ++kt)
#pragma unroll
                for (int r = 0; r < 4; ++r) {
                    const float p = exp2f(s[qt][kt][r] - mn);
                    s[qt][kt][r] = p;
                    sum += p;
                }
            sum += __shfl_xor(sum, 16, 64);
            sum += __shfl_xor(sum, 32, 64);
            l_run[qt] = l_run[qt] * resc[qt] + sum;
            m_run[qt] = mn;
        }

        // Rescale O accumulators (translate resc from q=row16 to q=lg*4+r).
#pragma unroll
        for (int qt = 0; qt < 2; ++qt)
#pragma unroll
            for (int r = 0; r < 4; ++r) {
                const float rr = __shfl(resc[qt], lg * 4 + r, 64);
                oac[qt][0][r] *= rr; oac[qt][1][r] *= rr;
                oac[qt][2][r] *= rr; oac[qt][3][r] *= rr;
            }

        // P -> bf16 -> per-wave LDS (A-fragment re-layout). The write->read
        // dependency is CROSS-LANE within the wave: fence it explicitly.
#pragma unroll
        for (int qt = 0; qt < 2; ++qt) {
            short* prow = &Pls[w * 2 + qt][row16 * 72];
#pragma unroll
            for (int kt = 0; kt < 4; ++kt) {
                bf16x4 pk;
#pragma unroll
                for (int r = 0; r < 4; ++r) pk[r] = f2bf(s[qt][kt][r]);
                *(bf16x4*)&prow[kt * 16 + lg * 4] = pk;
            }
        }
        asm volatile("s_waitcnt lgkmcnt(0)" ::: "memory");
        bf16x8 pf[2][2];
#pragma unroll
        for (int qt = 0; qt < 2; ++qt)
#pragma unroll
            for (int kk = 0; kk < 2; ++kk)
                pf[qt][kk] = *(const bf16x8*)&Pls[w * 2 + qt][row16 * 72 + kk * 32 + lg * 8];
        asm volatile("" ::: "memory");  // next iter's P stores must not hoist above

        // PV: oac[qt][dt] += P(16x64) · V(64x16), V^T B-frags from global.
#pragma unroll
        for (int dt = 0; dt < 4; ++dt) {
            const int vrow = dt * 16 + row16;
#pragma unroll
            for (int kk = 0; kk < 2; ++kk) {
                bf16x8 vf = *(const bf16x8*)&vbase[(size_t)vrow * 2048 + kvn + kk * 32 + lg * 8];
                oac[0][dt] = __builtin_amdgcn_mfma_f32_16x16x32_bf16(pf[0][kk], vf, oac[0][dt], 0, 0, 0);
                oac[1][dt] = __builtin_amdgcn_mfma_f32_16x16x32_bf16(pf[1][kk], vf, oac[1][dt], 0, 0, 0);
            }
        }
    }

    // Epilogue: divide by l (translated to q=lg*4+r layout) and store.
    const int b = bh >> 4, h = bh & 15;
    const float inv0 = 1.f / l_run[0], inv1 = 1.f / l_run[1];
#pragma unroll
    for (int qt = 0; qt < 2; ++qt) {
#pragma unroll
        for (int r = 0; r < 4; ++r) {
            const float iv = __shfl(qt == 0 ? inv0 : inv1, lg * 4 + r, 64);
            const int qrow = q0 + qt * 16 + lg * 4 + r;
#pragma unroll
            for (int dt = 0; dt < 4; ++dt) {
                const int c = h * 64 + dt * 16 + row16;
                aout[((size_t)b * 2048 + qrow) * 1024 + c] = f2bf(oac[qt][dt][r] * iv);
            }
        }
    }
}

// ---------------------------------------------------------------------------
extern "C" void kernel_launch(void* const* d_in, const int* in_sizes, int n_in,
                              void* d_out, int out_size, void* d_ws, size_t ws_size,
                              hipStream_t stream) {
    const float* q  = (const float*)d_in[0];
    const float* k  = (const float*)d_in[1];
    const float* v  = (const float*)d_in[2];
    const float* Wq = (const float*)d_in[3];
    const float* bq = (const float*)d_in[4];
    const float* Wk = (const float*)d_in[5];
    const float* bk = (const float*)d_in[6];
    const float* Wv = (const float*)d_in[7];
    const float* bv = (const float*)d_in[8];
    const float* Wo = (const float*)d_in[9];
    const float* bo = (const float*)d_in[10];

    char* ws = (char*)d_ws;
    short* wt   = (short*)ws;                     // 4 x 2 MiB bf16 W^T
    short* qh   = (short*)(ws + (8u  << 20));     // 8 MiB [b,h,n,d]
    short* khp  = (short*)(ws + (16u << 20));     // 8 MiB [b,h,n,d]
    short* vt   = (short*)(ws + (24u << 20));     // 8 MiB [b,h,d,n]
    short* aout = (short*)(ws + (32u << 20));     // 8 MiB [b,n,c]

    const float qscale = 0.125f * 1.44269504088896340736f;  // 1/sqrt(D) * log2(e)

    prep_w<<<dim3(32, 32, 4), 256, 0, stream>>>(Wq, Wk, Wv, Wo, wt);
    dim3 gg(32, 8);
    gemm_kernel<1><<<gg, 256, 0, stream>>>(q, wt,           bq, qh,   0, qscale);
    gemm_kernel<1><<<gg, 256, 0, stream>>>(k, wt + 1048576, bk, khp,  0, 1.0f);
    gemm_kernel<1><<<gg, 256, 0, stream>>>(v, wt + 2097152, bv, vt,   1, 1.0f);
    attn_kernel<<<dim3(16, 32), 256, 0, stream>>>(qh, khp, vt, aout);
    gemm_kernel<0><<<gg, 256, 0, stream>>>(aout, wt + 3145728, bo, d_out, 2, 1.0f);
}